// Round 8
// baseline (414.544 us; speedup 1.0000x reference)
//
#include <hip/hip_runtime.h>

typedef _Float16 f16;
typedef _Float16 f16x2 __attribute__((ext_vector_type(2)));
typedef _Float16 f16x4 __attribute__((ext_vector_type(4)));
typedef _Float16 f16x8 __attribute__((ext_vector_type(8)));
typedef float f32x4 __attribute__((ext_vector_type(4)));

#define NT 64
#define CH 192
#define NH 6
#define MH 256
#define BWIN 4096
#define LOG2E 1.44269504f

#define STOK 200            // tok/ao row stride (f16): 400 B
#define WIN_BYTES 49152     // per-window LDS region (qk overlay is the max)
#define SMEM_BYTES (2 * WIN_BYTES)

#define MFMA16(a, b, c) __builtin_amdgcn_mfma_f32_16x16x16f16(a, b, c, 0, 0, 0)
#define MFMA32(a, b, c) __builtin_amdgcn_mfma_f32_16x16x32_f16(a, b, c, 0, 0, 0)

// swizzled index into a [64][32] f16 qk tile: 4 chunks of 8 f16 per row,
// chunk' = (chunk + (n>>1)) & 3  -> conflict-free b128 reads at 64B rows
__device__ __forceinline__ int qkidx(int n, int d) {
    return n * 32 + ((((d >> 3) + (n >> 1)) & 3) << 3) + (d & 7);
}

// ---------------- bias table (natural layout bias[h][n][m]) ----------------
__global__ void bias_kernel(const float* __restrict__ mW1, const float* __restrict__ mb1,
                            const float* __restrict__ mW2, const float* __restrict__ mb2,
                            float* __restrict__ bias_tbl) {
    int p = blockIdx.x * blockDim.x + threadIdx.x;
    if (p >= NT * NT) return;
    int n = p >> 6, m = p & 63;
    float di = (float)((n >> 3) - (m >> 3));
    float dj = (float)((n & 7) - (m & 7));
    float r0 = copysignf(log1pf(fabsf(di)), di);
    float r1 = copysignf(log1pf(fabsf(dj)), dj);
    float acc[NH];
#pragma unroll
    for (int h = 0; h < NH; h++) acc[h] = mb2[h];
    for (int k = 0; k < MH; k++) {
        float hv = fmaxf(r0 * mW1[k] + r1 * mW1[MH + k] + mb1[k], 0.0f);
#pragma unroll
        for (int h = 0; h < NH; h++) acc[h] += hv * mW2[k * NH + h];
    }
#pragma unroll
    for (int h = 0; h < NH; h++) bias_tbl[h * (NT * NT) + p] = acc[h];
}

// ---------------- fragment-packed weight prep ----------------
// Wpk[ct<36][ks<6][lane<64][t<8] = Wqkv[c][o], o=16ct+(lane&15), c=ks*32+(lane>>4)*8+t
// Wpp[ct<12][ks<6][lane<64][t<8] = Wproj[c][o]
__global__ void prep_kernel(const float* __restrict__ Wqkv, const float* __restrict__ Wproj,
                            f16* __restrict__ Wpk, f16* __restrict__ Wpp) {
    int i = blockIdx.x * blockDim.x + threadIdx.x;
    const int NQ = 36 * 6 * 64 * 8;
    if (i < NQ) {
        int t = i & 7, lane = (i >> 3) & 63, ks = (i >> 9) % 6, ct = i >> 9; ct /= 6;
        int o = 16 * ct + (lane & 15);
        int c = ks * 32 + (lane >> 4) * 8 + t;
        Wpk[i] = (f16)Wqkv[c * 576 + o];
    } else if (i < NQ + 12 * 6 * 64 * 8) {
        int j = i - NQ;
        int t = j & 7, lane = (j >> 3) & 63, ks = (j >> 9) % 6, ct = j >> 9; ct /= 6;
        int o = 16 * ct + (lane & 15);
        int c = ks * 32 + (lane >> 4) * 8 + t;
        Wpp[j] = (f16)Wproj[c * 192 + o];
    }
}

// ---------------- combined (mask + bias) * log2e table ----------------
__global__ void comb_kernel(const float* __restrict__ mask, const float* __restrict__ bias_tbl,
                            float* __restrict__ comb) {
    int j = blockIdx.x * blockDim.x + threadIdx.x;
    if (j >= 64 * NH * NT * NT) return;
    int im = j / (NH * NT * NT);
    int rem = j % (NH * NT * NT);
    int h = rem >> 12;
    int p = rem & 4095;
    comb[j] = (mask[im * 4096 + p] + bias_tbl[h * 4096 + p]) * LOG2E;
}

// qkv pass over both windows with shared weight fragments.
// TRANS: D[d][n] = W^T tok^T (Q,K); else natural D[m][d] = tok W (V).
template <bool TRANS>
__device__ __forceinline__ void qkv_pass(const f16* tokA, const f16* tokB,
                                         const f16* __restrict__ Wpk, int ctbase,
                                         int c16, int g4, int l,
                                         f32x4 (&accA)[2][4], f32x4 (&accB)[2][4]) {
#pragma unroll
    for (int ks = 0; ks < 6; ks++) {
        f16x8 afA[4], afB[4];
#pragma unroll
        for (int nt = 0; nt < 4; nt++) {
            afA[nt] = *(const f16x8*)(tokA + (16 * nt + c16) * STOK + ks * 32 + 8 * g4);
            afB[nt] = *(const f16x8*)(tokB + (16 * nt + c16) * STOK + ks * 32 + 8 * g4);
        }
#pragma unroll
        for (int dt = 0; dt < 2; dt++) {
            f16x8 wf = *(const f16x8*)(Wpk + (((size_t)(ctbase + dt) * 6 + ks) * 64 + l) * 8);
#pragma unroll
            for (int nt = 0; nt < 4; nt++) {
                if (TRANS) {
                    accA[dt][nt] = MFMA32(wf, afA[nt], accA[dt][nt]);
                    accB[dt][nt] = MFMA32(wf, afB[nt], accB[dt][nt]);
                } else {
                    accA[dt][nt] = MFMA32(afA[nt], wf, accA[dt][nt]);
                    accB[dt][nt] = MFMA32(afB[nt], wf, accB[dt][nt]);
                }
            }
        }
    }
}

// l2-normalize (transposed layout: lane=n, reg=d) + pack to f16 frags
__device__ __forceinline__ void norm_pack(const f32x4 (&acc)[2][4], const float* __restrict__ bq,
                                          int w, int g4, f16x4 (&h)[2][4]) {
    f32x4 bb0 = *(const f32x4*)(bq + 32 * w + 4 * g4);
    f32x4 bb1 = *(const f32x4*)(bq + 32 * w + 16 + 4 * g4);
#pragma unroll
    for (int nt = 0; nt < 4; nt++) {
        float a0[4], a1[4];
        float ss = 0.f;
#pragma unroll
        for (int r = 0; r < 4; r++) {
            a0[r] = acc[0][nt][r] + bb0[r];
            a1[r] = acc[1][nt][r] + bb1[r];
            ss += a0[r] * a0[r] + a1[r] * a1[r];
        }
        ss += __shfl_xor(ss, 16);
        ss += __shfl_xor(ss, 32);
        float inv = 1.0f / fmaxf(sqrtf(ss), 1e-12f);
#pragma unroll
        for (int r = 0; r < 4; r++) {
            h[0][nt][r] = (f16)(a0[r] * inv);
            h[1][nt][r] = (f16)(a1[r] * inv);
        }
    }
}

// attention for one window/head: S^T -> softmax -> PV (av out in regs)
__device__ __forceinline__ void attn_one(const f16* qh, const f16* kh,
                                         const float* __restrict__ cb, float itau_l2,
                                         const f16x4 (&vb)[2][4], int c16, int g4,
                                         f32x4 (&av)[4][2]) {
    f32x4 sv[4][4];   // [mt][nt]
    {
        f16x8 aqf[4];
#pragma unroll
        for (int t = 0; t < 4; t++)
            aqf[t] = *(const f16x8*)(qh + qkidx(16 * t + c16, 8 * g4));
#pragma unroll
        for (int mt = 0; mt < 4; mt++) {
            f16x8 akf = *(const f16x8*)(kh + qkidx(16 * mt + c16, 8 * g4));
#pragma unroll
            for (int nt = 0; nt < 4; nt++) {
                f32x4 z = {};
                sv[mt][nt] = MFMA32(akf, aqf[nt], z);
            }
        }
    }
    // epilogue: sv*itau*log2e + comb (pre-scaled by log2e)
#pragma unroll
    for (int mt = 0; mt < 4; mt++)
#pragma unroll
        for (int nt = 0; nt < 4; nt++) {
            f32x4 cc = *(const f32x4*)(cb + (16 * nt + c16) * NT + 16 * mt + 4 * g4);
#pragma unroll
            for (int r = 0; r < 4; r++)
                sv[mt][nt][r] = sv[mt][nt][r] * itau_l2 + cc[r];
        }
    // softmax over m, fold 1/sum
#pragma unroll
    for (int nt = 0; nt < 4; nt++) {
        float mx = sv[0][nt][0];
#pragma unroll
        for (int mt = 0; mt < 4; mt++)
#pragma unroll
            for (int r = 0; r < 4; r++) mx = fmaxf(mx, sv[mt][nt][r]);
        mx = fmaxf(mx, __shfl_xor(mx, 16));
        mx = fmaxf(mx, __shfl_xor(mx, 32));
        float sum = 0.f;
#pragma unroll
        for (int mt = 0; mt < 4; mt++)
#pragma unroll
            for (int r = 0; r < 4; r++) {
                float p = exp2f(sv[mt][nt][r] - mx);
                sv[mt][nt][r] = p;
                sum += p;
            }
        sum += __shfl_xor(sum, 16);
        sum += __shfl_xor(sum, 32);
        float ris = 1.0f / sum;
#pragma unroll
        for (int mt = 0; mt < 4; mt++)
#pragma unroll
            for (int r = 0; r < 4; r++) sv[mt][nt][r] *= ris;
    }
    // P -> f16 a-frags, PV all-register
    f16x4 pa[4][4];
#pragma unroll
    for (int mk = 0; mk < 4; mk++)
#pragma unroll
        for (int nt = 0; nt < 4; nt++) {
            f16x4 h;
#pragma unroll
            for (int r = 0; r < 4; r++) h[r] = (f16)sv[mk][nt][r];
            pa[mk][nt] = h;
        }
#pragma unroll
    for (int nt = 0; nt < 4; nt++)
#pragma unroll
        for (int dt = 0; dt < 2; dt++) {
            f32x4 z = {};
            av[nt][dt] = z;
        }
#pragma unroll
    for (int mk = 0; mk < 4; mk++)
#pragma unroll
        for (int nt = 0; nt < 4; nt++)
#pragma unroll
            for (int dt = 0; dt < 2; dt++)
                av[nt][dt] = MFMA16(pa[mk][nt], vb[dt][mk], av[nt][dt]);
}

// ---------------- main kernel: 1 block = 2 windows, 6 waves, wave = head ----------------
__launch_bounds__(384)
__global__ void attn_kernel(const float* __restrict__ x, const float* __restrict__ bqkv,
                            const float* __restrict__ bproj, const float* __restrict__ tau,
                            const f16* __restrict__ Wpk, const f16* __restrict__ Wpp,
                            const float* __restrict__ comb, float* __restrict__ out) {
    __shared__ __align__(16) char smem[SMEM_BYTES];

    const int tid = threadIdx.x;
    const int l   = tid & 63;
    const int w   = __builtin_amdgcn_readfirstlane(tid >> 6);   // head 0..5
    const int b0  = blockIdx.x * 2;
    const int b1  = b0 + 1;
    const int c16 = l & 15;
    const int g4  = l >> 4;

    f16* tokA = (f16*)smem;                 // window A region (tok/qk/ao overlay)
    f16* tokB = (f16*)(smem + WIN_BYTES);   // window B region
    f16* qkA  = tokA;
    f16* qkB  = tokB;
    f16* aoA  = tokA;
    f16* aoB  = tokB;

    // ---- phase 0: stage x[b0], x[b1] -> tok f16 [n][c] (16 parallel HBM loads) ----
    {
        const int n4 = 4 * c16;
#pragma unroll
        for (int wp = 0; wp < 2; wp++) {
            const float* xb = x + (size_t)(b0 + wp) * (CH * NT);
            f16* tok = wp ? tokB : tokA;
#pragma unroll
            for (int i = 0; i < 4; i++) {
                int c = 32 * w + 8 * g4 + 2 * i;
                f32x4 a0 = *(const f32x4*)(xb + c * NT + n4);
                f32x4 a1 = *(const f32x4*)(xb + (c + 1) * NT + n4);
#pragma unroll
                for (int j = 0; j < 4; j++) {
                    f16x2 p;
                    p[0] = (f16)a0[j];
                    p[1] = (f16)a1[j];
                    *(f16x2*)(tok + (n4 + j) * STOK + c) = p;
                }
            }
        }
    }
    __syncthreads();

    // ---- phase 1: qkv (Q, K transposed; V natural), both windows, shared weights ----
    f16x4 hqA[2][4], hqB[2][4], hkA[2][4], hkB[2][4];
    f16x4 vbA[2][4], vbB[2][4];
    {
        f32x4 accA[2][4] = {}, accB[2][4] = {};
        qkv_pass<true>(tokA, tokB, Wpk, 2 * w, c16, g4, l, accA, accB);
        norm_pack(accA, bqkv, w, g4, hqA);
        norm_pack(accB, bqkv, w, g4, hqB);
    }
    {
        f32x4 accA[2][4] = {}, accB[2][4] = {};
        qkv_pass<true>(tokA, tokB, Wpk, 12 + 2 * w, c16, g4, l, accA, accB);
        norm_pack(accA, bqkv + CH, w, g4, hkA);
        norm_pack(accB, bqkv + CH, w, g4, hkB);
    }
    {
        f32x4 accA[2][4] = {}, accB[2][4] = {};
        qkv_pass<false>(tokA, tokB, Wpk, 24 + 2 * w, c16, g4, l, accA, accB);
#pragma unroll
        for (int dt = 0; dt < 2; dt++) {
            float bb = bqkv[384 + 32 * w + 16 * dt + c16];
#pragma unroll
            for (int mt = 0; mt < 4; mt++)
#pragma unroll
                for (int r = 0; r < 4; r++) {
                    vbA[dt][mt][r] = (f16)(accA[dt][mt][r] + bb);
                    vbB[dt][mt][r] = (f16)(accB[dt][mt][r] + bb);
                }
        }
    }

    __syncthreads();   // all tok reads done -> qk may overlay

    // ---- write Qhat/Khat (swizzled) for both windows ----
    f16* qhA = qkA + (w * 2 + 0) * 2048;
    f16* khA = qkA + (w * 2 + 1) * 2048;
    f16* qhB = qkB + (w * 2 + 0) * 2048;
    f16* khB = qkB + (w * 2 + 1) * 2048;
#pragma unroll
    for (int nt = 0; nt < 4; nt++)
#pragma unroll
        for (int dt = 0; dt < 2; dt++) {
            int base = qkidx(16 * nt + c16, 16 * dt + 4 * g4);
            *(f16x2*)(qhA + base)     = f16x2{hqA[dt][nt][0], hqA[dt][nt][1]};
            *(f16x2*)(qhA + base + 2) = f16x2{hqA[dt][nt][2], hqA[dt][nt][3]};
            *(f16x2*)(khA + base)     = f16x2{hkA[dt][nt][0], hkA[dt][nt][1]};
            *(f16x2*)(khA + base + 2) = f16x2{hkA[dt][nt][2], hkA[dt][nt][3]};
            *(f16x2*)(qhB + base)     = f16x2{hqB[dt][nt][0], hqB[dt][nt][1]};
            *(f16x2*)(qhB + base + 2) = f16x2{hqB[dt][nt][2], hqB[dt][nt][3]};
            *(f16x2*)(khB + base)     = f16x2{hkB[dt][nt][0], hkB[dt][nt][1]};
            *(f16x2*)(khB + base + 2) = f16x2{hkB[dt][nt][2], hkB[dt][nt][3]};
        }

    // ---- phase 2: attention A then B (independent chains; compiler interleaves) ----
    const float itau_l2 = LOG2E / fmaxf(tau[w], 0.01f);
    const float* cbA = comb + ((size_t)((b0 & 63) * NH + w)) * (NT * NT);
    const float* cbB = comb + ((size_t)((b1 & 63) * NH + w)) * (NT * NT);
    f32x4 avA[4][2], avB[4][2];
    attn_one(qhA, khA, cbA, itau_l2, vbA, c16, g4, avA);
    attn_one(qhB, khB, cbB, itau_l2, vbB, c16, g4, avB);

    __syncthreads();   // all qk reads done -> ao may overlay

#pragma unroll
    for (int nt = 0; nt < 4; nt++)
#pragma unroll
        for (int dt = 0; dt < 2; dt++)
#pragma unroll
            for (int r = 0; r < 4; r++) {
                aoA[(16 * nt + 4 * g4 + r) * STOK + 32 * w + 16 * dt + c16] = (f16)avA[nt][dt][r];
                aoB[(16 * nt + 4 * g4 + r) * STOK + 32 * w + 16 * dt + c16] = (f16)avB[nt][dt][r];
            }
    __syncthreads();

    // ---- phase 3: proj GEMM, both windows, shared weight fragments ----
    f32x4 acc2A[2][4] = {}, acc2B[2][4] = {};
#pragma unroll
    for (int ks = 0; ks < 6; ks++) {
        f16x8 afA[4], afB[4];
#pragma unroll
        for (int rt = 0; rt < 4; rt++) {
            afA[rt] = *(const f16x8*)(aoA + (16 * rt + c16) * STOK + ks * 32 + 8 * g4);
            afB[rt] = *(const f16x8*)(aoB + (16 * rt + c16) * STOK + ks * 32 + 8 * g4);
        }
#pragma unroll
        for (int c2 = 0; c2 < 2; c2++) {
            f16x8 bw = *(const f16x8*)(Wpp + (((size_t)(2 * w + c2) * 6 + ks) * 64 + l) * 8);
#pragma unroll
            for (int rt = 0; rt < 4; rt++) {
                acc2A[c2][rt] = MFMA32(afA[rt], bw, acc2A[c2][rt]);
                acc2B[c2][rt] = MFMA32(afB[rt], bw, acc2B[c2][rt]);
            }
        }
    }
    float* obA = out + (size_t)b0 * (CH * NT);
    float* obB = out + (size_t)b1 * (CH * NT);
#pragma unroll
    for (int c2 = 0; c2 < 2; c2++) {
        int c = 16 * (2 * w + c2) + c16;
        float bp = bproj[c];
#pragma unroll
        for (int rt = 0; rt < 4; rt++) {
            f32x4 oA = acc2A[c2][rt];
            f32x4 oB = acc2B[c2][rt];
#pragma unroll
            for (int r = 0; r < 4; r++) { oA[r] += bp; oB[r] += bp; }
            *(f32x4*)(obA + c * NT + 16 * rt + 4 * g4) = oA;
            *(f32x4*)(obB + c * NT + 16 * rt + 4 * g4) = oB;
        }
    }
}

// ---------------- launcher ----------------
#define WS_BIAS 0
#define WS_WPK  98304
#define WS_WPP  319488
#define WS_COMB 393216

extern "C" void kernel_launch(void* const* d_in, const int* in_sizes, int n_in,
                              void* d_out, int out_size, void* d_ws, size_t ws_size,
                              hipStream_t stream) {
    const float* x     = (const float*)d_in[0];
    const float* mask  = (const float*)d_in[1];
    const float* Wqkv  = (const float*)d_in[2];
    const float* bqkv  = (const float*)d_in[3];
    const float* Wproj = (const float*)d_in[4];
    const float* bproj = (const float*)d_in[5];
    const float* mW1   = (const float*)d_in[6];
    const float* mb1   = (const float*)d_in[7];
    const float* mW2   = (const float*)d_in[8];
    const float* mb2   = (const float*)d_in[9];
    const float* tau   = (const float*)d_in[10];

    char* ws = (char*)d_ws;
    float* bias_tbl = (float*)(ws + WS_BIAS);
    f16*   Wpk      = (f16*)(ws + WS_WPK);
    f16*   Wpp      = (f16*)(ws + WS_WPP);
    float* comb     = (float*)(ws + WS_COMB);

    bias_kernel<<<16, 256, 0, stream>>>(mW1, mb1, mW2, mb2, bias_tbl);
    int prep_n = 36 * 6 * 64 * 8 + 12 * 6 * 64 * 8;
    prep_kernel<<<(prep_n + 255) / 256, 256, 0, stream>>>(Wqkv, Wproj, Wpk, Wpp);
    int comb_n = 64 * NH * NT * NT;
    comb_kernel<<<(comb_n + 255) / 256, 256, 0, stream>>>(mask, bias_tbl, comb);
    attn_kernel<<<BWIN / 2, 384, 0, stream>>>(x, bqkv, bproj, tau, Wpk, Wpp, comb,
                                              (float*)d_out);
}

// Round 9
// 389.395 us; speedup vs baseline: 1.0646x; 1.0646x over previous
//
#include <hip/hip_runtime.h>

typedef _Float16 f16;
typedef _Float16 f16x2 __attribute__((ext_vector_type(2)));
typedef _Float16 f16x4 __attribute__((ext_vector_type(4)));
typedef _Float16 f16x8 __attribute__((ext_vector_type(8)));
typedef float f32x4 __attribute__((ext_vector_type(4)));

#define NT 64
#define CH 192
#define NH 6
#define MH 256
#define BWIN 4096
#define LOG2E 1.44269504f

#define STOK 200            // tok/ao row stride (f16): 400 B
#define SMEM_BYTES 49152    // overlay: qk 12*[64][32] f16 = 49152 ; tok/ao 25600

#define MFMA16(a, b, c) __builtin_amdgcn_mfma_f32_16x16x16f16(a, b, c, 0, 0, 0)
#define MFMA32(a, b, c) __builtin_amdgcn_mfma_f32_16x16x32_f16(a, b, c, 0, 0, 0)

// swizzled index into a [64][32] f16 qk tile: 4 chunks of 8 f16 per row,
// chunk' = (chunk + (n>>1)) & 3  -> conflict-free b128 reads at 64B rows
__device__ __forceinline__ int qkidx(int n, int d) {
    return n * 32 + ((((d >> 3) + (n >> 1)) & 3) << 3) + (d & 7);
}

// ---------------- bias table (natural layout bias[h][n][m]) ----------------
__global__ void bias_kernel(const float* __restrict__ mW1, const float* __restrict__ mb1,
                            const float* __restrict__ mW2, const float* __restrict__ mb2,
                            float* __restrict__ bias_tbl) {
    int p = blockIdx.x * blockDim.x + threadIdx.x;
    if (p >= NT * NT) return;
    int n = p >> 6, m = p & 63;
    float di = (float)((n >> 3) - (m >> 3));
    float dj = (float)((n & 7) - (m & 7));
    float r0 = copysignf(log1pf(fabsf(di)), di);
    float r1 = copysignf(log1pf(fabsf(dj)), dj);
    float acc[NH];
#pragma unroll
    for (int h = 0; h < NH; h++) acc[h] = mb2[h];
    for (int k = 0; k < MH; k++) {
        float hv = fmaxf(r0 * mW1[k] + r1 * mW1[MH + k] + mb1[k], 0.0f);
#pragma unroll
        for (int h = 0; h < NH; h++) acc[h] += hv * mW2[k * NH + h];
    }
#pragma unroll
    for (int h = 0; h < NH; h++) bias_tbl[h * (NT * NT) + p] = acc[h];
}

// ---------------- fragment-packed weight prep ----------------
// Wpk[ct<36][ks<6][lane<64][t<8] = Wqkv[c][o], o=16ct+(lane&15), c=ks*32+(lane>>4)*8+t
// Wpp[ct<12][ks<6][lane<64][t<8] = Wproj[c][o]
__global__ void prep_kernel(const float* __restrict__ Wqkv, const float* __restrict__ Wproj,
                            f16* __restrict__ Wpk, f16* __restrict__ Wpp) {
    int i = blockIdx.x * blockDim.x + threadIdx.x;
    const int NQ = 36 * 6 * 64 * 8;
    if (i < NQ) {
        int t = i & 7, lane = (i >> 3) & 63, ks = (i >> 9) % 6, ct = i >> 9; ct /= 6;
        int o = 16 * ct + (lane & 15);
        int c = ks * 32 + (lane >> 4) * 8 + t;
        Wpk[i] = (f16)Wqkv[c * 576 + o];
    } else if (i < NQ + 12 * 6 * 64 * 8) {
        int j = i - NQ;
        int t = j & 7, lane = (j >> 3) & 63, ks = (j >> 9) % 6, ct = j >> 9; ct /= 6;
        int o = 16 * ct + (lane & 15);
        int c = ks * 32 + (lane >> 4) * 8 + t;
        Wpp[j] = (f16)Wproj[c * 192 + o];
    }
}

// ---------------- combined (mask + bias) * log2e table ----------------
__global__ void comb_kernel(const float* __restrict__ mask, const float* __restrict__ bias_tbl,
                            float* __restrict__ comb) {
    int j = blockIdx.x * blockDim.x + threadIdx.x;
    if (j >= 64 * NH * NT * NT) return;
    int im = j / (NH * NT * NT);
    int rem = j % (NH * NT * NT);
    int h = rem >> 12;
    int p = rem & 4095;
    comb[j] = (mask[im * 4096 + p] + bias_tbl[h * 4096 + p]) * LOG2E;
}

// ---------------- main kernel: 1 block = 1 window, 12 waves ----------------
// wave v = 2*w + h : head w (0..5), row-half h (0..1) -> query/key rows [32h, 32h+32)
__launch_bounds__(768)
__global__ void attn_kernel(const float* __restrict__ x, const float* __restrict__ bqkv,
                            const float* __restrict__ bproj, const float* __restrict__ tau,
                            const f16* __restrict__ Wpk, const f16* __restrict__ Wpp,
                            const float* __restrict__ comb, float* __restrict__ out) {
    __shared__ __align__(16) char smem[SMEM_BYTES];
    f16* tok = (f16*)smem;   // [64][STOK]
    f16* qk  = (f16*)smem;   // 12 x swizzled [64][32] tiles (per head: Qhat, Khat)
    f16* ao  = (f16*)smem;   // [64][STOK]

    const int tid = threadIdx.x;
    const int l   = tid & 63;
    const int v   = __builtin_amdgcn_readfirstlane(tid >> 6);   // 0..11
    const int w   = v >> 1;                                     // head
    const int h   = v & 1;                                      // row half
    const int b   = blockIdx.x;
    const int c16 = l & 15;
    const int g4  = l >> 4;

    // ---- phase 0: stage x[b] (fp32 [c][n]) -> tok f16 [n][c]; wave stages 16 channels ----
    {
        const float* xb = x + (size_t)b * (CH * NT);
        const int n4 = 4 * c16;
#pragma unroll
        for (int i = 0; i < 2; i++) {
            int c = 16 * v + 4 * g4 + 2 * i;
            f32x4 a0 = *(const f32x4*)(xb + c * NT + n4);
            f32x4 a1 = *(const f32x4*)(xb + (c + 1) * NT + n4);
#pragma unroll
            for (int j = 0; j < 4; j++) {
                f16x2 p;
                p[0] = (f16)a0[j];
                p[1] = (f16)a1[j];
                *(f16x2*)(tok + (n4 + j) * STOK + c) = p;
            }
        }
    }
    __syncthreads();

    // ---- phase 1: qkv. Q,K transposed for own row-half; V natural, full (duplicated) ----
    f16x4 hq[2][2], hk[2][2];   // [dt][ntl] normalized fragments for own rows
    f16x4 vb[2][4];             // [dt][mk]  full V PV B-frags
    {   // pass Q
        f32x4 acc[2][2] = {};
#pragma unroll
        for (int ks = 0; ks < 6; ks++) {
            f16x8 af[2];
#pragma unroll
            for (int ntl = 0; ntl < 2; ntl++)
                af[ntl] = *(const f16x8*)(tok + (16 * (2 * h + ntl) + c16) * STOK + ks * 32 + 8 * g4);
#pragma unroll
            for (int dt = 0; dt < 2; dt++) {
                f16x8 wf = *(const f16x8*)(Wpk + (((size_t)(2 * w + dt) * 6 + ks) * 64 + l) * 8);
#pragma unroll
                for (int ntl = 0; ntl < 2; ntl++)
                    acc[dt][ntl] = MFMA32(wf, af[ntl], acc[dt][ntl]);
            }
        }
        f32x4 bb0 = *(const f32x4*)(bqkv + 32 * w + 4 * g4);
        f32x4 bb1 = *(const f32x4*)(bqkv + 32 * w + 16 + 4 * g4);
#pragma unroll
        for (int ntl = 0; ntl < 2; ntl++) {
            float a0[4], a1[4];
            float ss = 0.f;
#pragma unroll
            for (int r = 0; r < 4; r++) {
                a0[r] = acc[0][ntl][r] + bb0[r];
                a1[r] = acc[1][ntl][r] + bb1[r];
                ss += a0[r] * a0[r] + a1[r] * a1[r];
            }
            ss += __shfl_xor(ss, 16);
            ss += __shfl_xor(ss, 32);
            float inv = 1.0f / fmaxf(sqrtf(ss), 1e-12f);
#pragma unroll
            for (int r = 0; r < 4; r++) {
                hq[0][ntl][r] = (f16)(a0[r] * inv);
                hq[1][ntl][r] = (f16)(a1[r] * inv);
            }
        }
    }
    {   // pass K
        f32x4 acc[2][2] = {};
#pragma unroll
        for (int ks = 0; ks < 6; ks++) {
            f16x8 af[2];
#pragma unroll
            for (int ntl = 0; ntl < 2; ntl++)
                af[ntl] = *(const f16x8*)(tok + (16 * (2 * h + ntl) + c16) * STOK + ks * 32 + 8 * g4);
#pragma unroll
            for (int dt = 0; dt < 2; dt++) {
                f16x8 wf = *(const f16x8*)(Wpk + (((size_t)(12 + 2 * w + dt) * 6 + ks) * 64 + l) * 8);
#pragma unroll
                for (int ntl = 0; ntl < 2; ntl++)
                    acc[dt][ntl] = MFMA32(wf, af[ntl], acc[dt][ntl]);
            }
        }
        f32x4 bb0 = *(const f32x4*)(bqkv + CH + 32 * w + 4 * g4);
        f32x4 bb1 = *(const f32x4*)(bqkv + CH + 32 * w + 16 + 4 * g4);
#pragma unroll
        for (int ntl = 0; ntl < 2; ntl++) {
            float a0[4], a1[4];
            float ss = 0.f;
#pragma unroll
            for (int r = 0; r < 4; r++) {
                a0[r] = acc[0][ntl][r] + bb0[r];
                a1[r] = acc[1][ntl][r] + bb1[r];
                ss += a0[r] * a0[r] + a1[r] * a1[r];
            }
            ss += __shfl_xor(ss, 16);
            ss += __shfl_xor(ss, 32);
            float inv = 1.0f / fmaxf(sqrtf(ss), 1e-12f);
#pragma unroll
            for (int r = 0; r < 4; r++) {
                hk[0][ntl][r] = (f16)(a0[r] * inv);
                hk[1][ntl][r] = (f16)(a1[r] * inv);
            }
        }
    }
    {   // pass V (full m range; both sibling waves duplicate)
        f32x4 acc[2][4] = {};
#pragma unroll
        for (int ks = 0; ks < 6; ks++) {
            f16x8 af[4];
#pragma unroll
            for (int mt = 0; mt < 4; mt++)
                af[mt] = *(const f16x8*)(tok + (16 * mt + c16) * STOK + ks * 32 + 8 * g4);
#pragma unroll
            for (int dt = 0; dt < 2; dt++) {
                f16x8 wf = *(const f16x8*)(Wpk + (((size_t)(24 + 2 * w + dt) * 6 + ks) * 64 + l) * 8);
#pragma unroll
                for (int mt = 0; mt < 4; mt++)
                    acc[dt][mt] = MFMA32(af[mt], wf, acc[dt][mt]);
            }
        }
#pragma unroll
        for (int dt = 0; dt < 2; dt++) {
            float bb = bqkv[384 + 32 * w + 16 * dt + c16];
#pragma unroll
            for (int mt = 0; mt < 4; mt++)
#pragma unroll
                for (int r = 0; r < 4; r++) vb[dt][mt][r] = (f16)(acc[dt][mt][r] + bb);
        }
    }

    __syncthreads();   // all tok reads done -> qk may overlay

    // ---- write own-half Qhat/Khat (swizzled tiles per head) ----
    {
        f16* qh = qk + (w * 2 + 0) * 2048;
        f16* kh = qk + (w * 2 + 1) * 2048;
#pragma unroll
        for (int ntl = 0; ntl < 2; ntl++)
#pragma unroll
            for (int dt = 0; dt < 2; dt++) {
                int base = qkidx(16 * (2 * h + ntl) + c16, 16 * dt + 4 * g4);
                *(f16x2*)(qh + base)     = f16x2{hq[dt][ntl][0], hq[dt][ntl][1]};
                *(f16x2*)(qh + base + 2) = f16x2{hq[dt][ntl][2], hq[dt][ntl][3]};
                *(f16x2*)(kh + base)     = f16x2{hk[dt][ntl][0], hk[dt][ntl][1]};
                *(f16x2*)(kh + base + 2) = f16x2{hk[dt][ntl][2], hk[dt][ntl][3]};
            }
    }
    __syncthreads();   // Khat halves visible across sibling waves

    // ---- phase 2: attention for own query rows ----
    f32x4 av[2][2];   // [ntl][dt]
    {
        const f16* qh = qk + (w * 2 + 0) * 2048;
        const f16* kh = qk + (w * 2 + 1) * 2048;
        f16x8 aqf[2];
#pragma unroll
        for (int ntl = 0; ntl < 2; ntl++)
            aqf[ntl] = *(const f16x8*)(qh + qkidx(16 * (2 * h + ntl) + c16, 8 * g4));
        f32x4 sv[4][2];   // [mt][ntl]
#pragma unroll
        for (int mt = 0; mt < 4; mt++) {
            f16x8 akf = *(const f16x8*)(kh + qkidx(16 * mt + c16, 8 * g4));
#pragma unroll
            for (int ntl = 0; ntl < 2; ntl++) {
                f32x4 z = {};
                sv[mt][ntl] = MFMA32(akf, aqf[ntl], z);
            }
        }
        const float itau_l2 = LOG2E / fmaxf(tau[w], 0.01f);
        const float* cb = comb + ((size_t)((b & 63) * NH + w)) * (NT * NT);
#pragma unroll
        for (int mt = 0; mt < 4; mt++)
#pragma unroll
            for (int ntl = 0; ntl < 2; ntl++) {
                f32x4 cc = *(const f32x4*)(cb + (16 * (2 * h + ntl) + c16) * NT + 16 * mt + 4 * g4);
#pragma unroll
                for (int r = 0; r < 4; r++)
                    sv[mt][ntl][r] = sv[mt][ntl][r] * itau_l2 + cc[r];
            }
        // softmax over m, fold 1/sum
#pragma unroll
        for (int ntl = 0; ntl < 2; ntl++) {
            float mx = sv[0][ntl][0];
#pragma unroll
            for (int mt = 0; mt < 4; mt++)
#pragma unroll
                for (int r = 0; r < 4; r++) mx = fmaxf(mx, sv[mt][ntl][r]);
            mx = fmaxf(mx, __shfl_xor(mx, 16));
            mx = fmaxf(mx, __shfl_xor(mx, 32));
            float sum = 0.f;
#pragma unroll
            for (int mt = 0; mt < 4; mt++)
#pragma unroll
                for (int r = 0; r < 4; r++) {
                    float p = exp2f(sv[mt][ntl][r] - mx);
                    sv[mt][ntl][r] = p;
                    sum += p;
                }
            sum += __shfl_xor(sum, 16);
            sum += __shfl_xor(sum, 32);
            float ris = 1.0f / sum;
#pragma unroll
            for (int mt = 0; mt < 4; mt++)
#pragma unroll
                for (int r = 0; r < 4; r++) sv[mt][ntl][r] *= ris;
        }
        // P -> f16 a-frags; PV all-register
        f16x4 pa[4][2];
#pragma unroll
        for (int mk = 0; mk < 4; mk++)
#pragma unroll
            for (int ntl = 0; ntl < 2; ntl++) {
                f16x4 hh;
#pragma unroll
                for (int r = 0; r < 4; r++) hh[r] = (f16)sv[mk][ntl][r];
                pa[mk][ntl] = hh;
            }
#pragma unroll
        for (int ntl = 0; ntl < 2; ntl++)
#pragma unroll
            for (int dt = 0; dt < 2; dt++) {
                f32x4 z = {};
                av[ntl][dt] = z;
            }
#pragma unroll
        for (int mk = 0; mk < 4; mk++)
#pragma unroll
            for (int ntl = 0; ntl < 2; ntl++)
#pragma unroll
                for (int dt = 0; dt < 2; dt++)
                    av[ntl][dt] = MFMA16(pa[mk][ntl], vb[dt][mk], av[ntl][dt]);
    }

    __syncthreads();   // all qk reads done -> ao may overlay

    // ao[n][c' = 32w+16dt+c16] for own rows
#pragma unroll
    for (int ntl = 0; ntl < 2; ntl++)
#pragma unroll
        for (int dt = 0; dt < 2; dt++)
#pragma unroll
            for (int r = 0; r < 4; r++)
                ao[(16 * (2 * h + ntl) + 4 * g4 + r) * STOK + 32 * w + 16 * dt + c16] =
                    (f16)av[ntl][dt][r];
    __syncthreads();

    // ---- phase 3: proj GEMM, wave v -> output c-tile v ----
    f32x4 acc2[4] = {};
#pragma unroll
    for (int ks = 0; ks < 6; ks++) {
        f16x8 af[4];
#pragma unroll
        for (int rt = 0; rt < 4; rt++)
            af[rt] = *(const f16x8*)(ao + (16 * rt + c16) * STOK + ks * 32 + 8 * g4);
        f16x8 bw = *(const f16x8*)(Wpp + (((size_t)v * 6 + ks) * 64 + l) * 8);
#pragma unroll
        for (int rt = 0; rt < 4; rt++)
            acc2[rt] = MFMA32(af[rt], bw, acc2[rt]);
    }
    float* ob = out + (size_t)b * (CH * NT);
    {
        int c = 16 * v + c16;
        float bp = bproj[c];
#pragma unroll
        for (int rt = 0; rt < 4; rt++) {
            f32x4 o4 = acc2[rt];
            o4[0] += bp; o4[1] += bp; o4[2] += bp; o4[3] += bp;
            *(f32x4*)(ob + c * NT + 16 * rt + 4 * g4) = o4;
        }
    }
}

// ---------------- launcher ----------------
#define WS_BIAS 0
#define WS_WPK  98304
#define WS_WPP  319488
#define WS_COMB 393216

extern "C" void kernel_launch(void* const* d_in, const int* in_sizes, int n_in,
                              void* d_out, int out_size, void* d_ws, size_t ws_size,
                              hipStream_t stream) {
    const float* x     = (const float*)d_in[0];
    const float* mask  = (const float*)d_in[1];
    const float* Wqkv  = (const float*)d_in[2];
    const float* bqkv  = (const float*)d_in[3];
    const float* Wproj = (const float*)d_in[4];
    const float* bproj = (const float*)d_in[5];
    const float* mW1   = (const float*)d_in[6];
    const float* mb1   = (const float*)d_in[7];
    const float* mW2   = (const float*)d_in[8];
    const float* mb2   = (const float*)d_in[9];
    const float* tau   = (const float*)d_in[10];

    char* ws = (char*)d_ws;
    float* bias_tbl = (float*)(ws + WS_BIAS);
    f16*   Wpk      = (f16*)(ws + WS_WPK);
    f16*   Wpp      = (f16*)(ws + WS_WPP);
    float* comb     = (float*)(ws + WS_COMB);

    bias_kernel<<<16, 256, 0, stream>>>(mW1, mb1, mW2, mb2, bias_tbl);
    int prep_n = 36 * 6 * 64 * 8 + 12 * 6 * 64 * 8;
    prep_kernel<<<(prep_n + 255) / 256, 256, 0, stream>>>(Wqkv, Wproj, Wpk, Wpp);
    int comb_n = 64 * NH * NT * NT;
    comb_kernel<<<(comb_n + 255) / 256, 256, 0, stream>>>(mask, bias_tbl, comb);
    attn_kernel<<<BWIN, 768, 0, stream>>>(x, bqkv, bproj, tau, Wpk, Wpp, comb,
                                          (float*)d_out);
}

// Round 10
// 349.438 us; speedup vs baseline: 1.1863x; 1.1143x over previous
//
#include <hip/hip_runtime.h>

typedef _Float16 f16;
typedef _Float16 f16x2 __attribute__((ext_vector_type(2)));
typedef _Float16 f16x4 __attribute__((ext_vector_type(4)));
typedef _Float16 f16x8 __attribute__((ext_vector_type(8)));
typedef float f32x4 __attribute__((ext_vector_type(4)));

#define NT 64
#define CH 192
#define NH 6
#define MH 256
#define BWIN 4096
#define LOG2E 1.44269504f

#define STOK 200            // tok/ao row stride (f16): 400 B
#define WIN_BYTES 49152     // per-window LDS region (qk overlay is the max)
#define SMEM_BYTES (2 * WIN_BYTES)

#define MFMA16(a, b, c) __builtin_amdgcn_mfma_f32_16x16x16f16(a, b, c, 0, 0, 0)
#define MFMA32(a, b, c) __builtin_amdgcn_mfma_f32_16x16x32_f16(a, b, c, 0, 0, 0)

// swizzled index into a [64][32] f16 qk tile: 4 chunks of 8 f16 per row,
// chunk' = (chunk + (n>>1)) & 3  -> conflict-free b128 reads at 64B rows
__device__ __forceinline__ int qkidx(int n, int d) {
    return n * 32 + ((((d >> 3) + (n >> 1)) & 3) << 3) + (d & 7);
}

// ---------------- bias table (natural layout bias[h][n][m]) ----------------
__global__ void bias_kernel(const float* __restrict__ mW1, const float* __restrict__ mb1,
                            const float* __restrict__ mW2, const float* __restrict__ mb2,
                            float* __restrict__ bias_tbl) {
    int p = blockIdx.x * blockDim.x + threadIdx.x;
    if (p >= NT * NT) return;
    int n = p >> 6, m = p & 63;
    float di = (float)((n >> 3) - (m >> 3));
    float dj = (float)((n & 7) - (m & 7));
    float r0 = copysignf(log1pf(fabsf(di)), di);
    float r1 = copysignf(log1pf(fabsf(dj)), dj);
    float acc[NH];
#pragma unroll
    for (int h = 0; h < NH; h++) acc[h] = mb2[h];
    for (int k = 0; k < MH; k++) {
        float hv = fmaxf(r0 * mW1[k] + r1 * mW1[MH + k] + mb1[k], 0.0f);
#pragma unroll
        for (int h = 0; h < NH; h++) acc[h] += hv * mW2[k * NH + h];
    }
#pragma unroll
    for (int h = 0; h < NH; h++) bias_tbl[h * (NT * NT) + p] = acc[h];
}

// ---------------- fragment-packed weight prep ----------------
// Wpk[ct<36][ks<6][lane<64][t<8] = Wqkv[c][o], o=16ct+(lane&15), c=ks*32+(lane>>4)*8+t
// Wpp[ct<12][ks<6][lane<64][t<8] = Wproj[c][o]
__global__ void prep_kernel(const float* __restrict__ Wqkv, const float* __restrict__ Wproj,
                            f16* __restrict__ Wpk, f16* __restrict__ Wpp) {
    int i = blockIdx.x * blockDim.x + threadIdx.x;
    const int NQ = 36 * 6 * 64 * 8;
    if (i < NQ) {
        int t = i & 7, lane = (i >> 3) & 63, ks = (i >> 9) % 6, ct = i >> 9; ct /= 6;
        int o = 16 * ct + (lane & 15);
        int c = ks * 32 + (lane >> 4) * 8 + t;
        Wpk[i] = (f16)Wqkv[c * 576 + o];
    } else if (i < NQ + 12 * 6 * 64 * 8) {
        int j = i - NQ;
        int t = j & 7, lane = (j >> 3) & 63, ks = (j >> 9) % 6, ct = j >> 9; ct /= 6;
        int o = 16 * ct + (lane & 15);
        int c = ks * 32 + (lane >> 4) * 8 + t;
        Wpp[j] = (f16)Wproj[c * 192 + o];
    }
}

// ---------------- combined (mask + bias) * log2e table ----------------
__global__ void comb_kernel(const float* __restrict__ mask, const float* __restrict__ bias_tbl,
                            float* __restrict__ comb) {
    int j = blockIdx.x * blockDim.x + threadIdx.x;
    if (j >= 64 * NH * NT * NT) return;
    int im = j / (NH * NT * NT);
    int rem = j % (NH * NT * NT);
    int h = rem >> 12;
    int p = rem & 4095;
    comb[j] = (mask[im * 4096 + p] + bias_tbl[h * 4096 + p]) * LOG2E;
}

// attention for one window/head: S^T -> softmax -> PV (av out in regs)
__device__ __forceinline__ void attn_one(const f16* qh, const f16* kh,
                                         const float* __restrict__ cb, float itau_l2,
                                         const f16x4 (&vb)[2][4], int c16, int g4,
                                         f32x4 (&av)[4][2]) {
    f32x4 sv[4][4];   // [mt][nt]
    {
        f16x8 aqf[4];
#pragma unroll
        for (int t = 0; t < 4; t++)
            aqf[t] = *(const f16x8*)(qh + qkidx(16 * t + c16, 8 * g4));
#pragma unroll
        for (int mt = 0; mt < 4; mt++) {
            f16x8 akf = *(const f16x8*)(kh + qkidx(16 * mt + c16, 8 * g4));
#pragma unroll
            for (int nt = 0; nt < 4; nt++) {
                f32x4 z = {};
                sv[mt][nt] = MFMA32(akf, aqf[nt], z);
            }
        }
    }
    // epilogue: sv*itau*log2e + comb (pre-scaled by log2e)
#pragma unroll
    for (int mt = 0; mt < 4; mt++)
#pragma unroll
        for (int nt = 0; nt < 4; nt++) {
            f32x4 cc = *(const f32x4*)(cb + (16 * nt + c16) * NT + 16 * mt + 4 * g4);
#pragma unroll
            for (int r = 0; r < 4; r++)
                sv[mt][nt][r] = sv[mt][nt][r] * itau_l2 + cc[r];
        }
    // softmax over m, fold 1/sum
#pragma unroll
    for (int nt = 0; nt < 4; nt++) {
        float mx = sv[0][nt][0];
#pragma unroll
        for (int mt = 0; mt < 4; mt++)
#pragma unroll
            for (int r = 0; r < 4; r++) mx = fmaxf(mx, sv[mt][nt][r]);
        mx = fmaxf(mx, __shfl_xor(mx, 16));
        mx = fmaxf(mx, __shfl_xor(mx, 32));
        float sum = 0.f;
#pragma unroll
        for (int mt = 0; mt < 4; mt++)
#pragma unroll
            for (int r = 0; r < 4; r++) {
                float p = exp2f(sv[mt][nt][r] - mx);
                sv[mt][nt][r] = p;
                sum += p;
            }
        sum += __shfl_xor(sum, 16);
        sum += __shfl_xor(sum, 32);
        float ris = 1.0f / sum;
#pragma unroll
        for (int mt = 0; mt < 4; mt++)
#pragma unroll
            for (int r = 0; r < 4; r++) sv[mt][nt][r] *= ris;
    }
    // P -> f16 a-frags, PV all-register
    f16x4 pa[4][4];
#pragma unroll
    for (int mk = 0; mk < 4; mk++)
#pragma unroll
        for (int nt = 0; nt < 4; nt++) {
            f16x4 h;
#pragma unroll
            for (int r = 0; r < 4; r++) h[r] = (f16)sv[mk][nt][r];
            pa[mk][nt] = h;
        }
#pragma unroll
    for (int nt = 0; nt < 4; nt++)
#pragma unroll
        for (int dt = 0; dt < 2; dt++) {
            f32x4 z = {};
            av[nt][dt] = z;
        }
#pragma unroll
    for (int mk = 0; mk < 4; mk++)
#pragma unroll
        for (int nt = 0; nt < 4; nt++)
#pragma unroll
            for (int dt = 0; dt < 2; dt++)
                av[nt][dt] = MFMA16(pa[mk][nt], vb[dt][mk], av[nt][dt]);
}

// ---------------- main kernel: 1 block = 2 windows, 12 waves ----------------
// waves 0-5 -> window 2*blockIdx.x (head = wave), waves 6-11 -> window 2*blockIdx.x+1
__launch_bounds__(768, 3)
__global__ void attn_kernel(const float* __restrict__ x, const float* __restrict__ bqkv,
                            const float* __restrict__ bproj, const float* __restrict__ tau,
                            const f16* __restrict__ Wpk, const f16* __restrict__ Wpp,
                            const float* __restrict__ comb, float* __restrict__ out) {
    __shared__ __align__(16) char smem[SMEM_BYTES];

    const int tid = threadIdx.x;
    const int l   = tid & 63;
    const int wv  = __builtin_amdgcn_readfirstlane(tid >> 6);   // 0..11
    const int win = wv >= NH ? 1 : 0;
    const int w   = wv - NH * win;                              // head 0..5
    const int b   = blockIdx.x * 2 + win;
    const int c16 = l & 15;
    const int g4  = l >> 4;

    f16* tok = (f16*)(smem + win * WIN_BYTES);   // [64][STOK] (own window region)
    f16* qk  = (f16*)(smem + win * WIN_BYTES);   // 12 x swizzled [64][32] tiles
    f16* ao  = (f16*)(smem + win * WIN_BYTES);   // [64][STOK]

    // ---- phase 0: stage own window's x (fp32 [c][n]) -> tok f16 [n][c] ----
    {
        const float* xb = x + (size_t)b * (CH * NT);
        const int n4 = 4 * c16;
#pragma unroll
        for (int i = 0; i < 4; i++) {
            int c = 32 * w + 8 * g4 + 2 * i;
            f32x4 a0 = *(const f32x4*)(xb + c * NT + n4);
            f32x4 a1 = *(const f32x4*)(xb + (c + 1) * NT + n4);
#pragma unroll
            for (int j = 0; j < 4; j++) {
                f16x2 p;
                p[0] = (f16)a0[j];
                p[1] = (f16)a1[j];
                *(f16x2*)(tok + (n4 + j) * STOK + c) = p;
            }
        }
    }
    __syncthreads();

    // ================= qkv: 3 light passes (Q, K transposed; V natural) ==========
    f16x4 hq[2][4], hk[2][4];   // normalized Qhat/Khat fragments [dt][nt]
    {
        f32x4 aq_[2][4] = {};
#pragma unroll
        for (int ks = 0; ks < 6; ks++) {
            f16x8 af[4];
#pragma unroll
            for (int nt = 0; nt < 4; nt++)
                af[nt] = *(const f16x8*)(tok + (16 * nt + c16) * STOK + ks * 32 + 8 * g4);
#pragma unroll
            for (int dt = 0; dt < 2; dt++) {
                f16x8 wf = *(const f16x8*)(Wpk + (((size_t)(2 * w + dt) * 6 + ks) * 64 + l) * 8);
#pragma unroll
                for (int nt = 0; nt < 4; nt++)
                    aq_[dt][nt] = MFMA32(wf, af[nt], aq_[dt][nt]);
            }
        }
#pragma unroll
        for (int dt = 0; dt < 2; dt++) {
            f32x4 bb = *(const f32x4*)(bqkv + 32 * w + 16 * dt + 4 * g4);
#pragma unroll
            for (int nt = 0; nt < 4; nt++)
#pragma unroll
                for (int r = 0; r < 4; r++) aq_[dt][nt][r] += bb[r];
        }
#pragma unroll
        for (int nt = 0; nt < 4; nt++) {
            float ss = 0.f;
#pragma unroll
            for (int dt = 0; dt < 2; dt++)
#pragma unroll
                for (int r = 0; r < 4; r++) ss += aq_[dt][nt][r] * aq_[dt][nt][r];
            ss += __shfl_xor(ss, 16);
            ss += __shfl_xor(ss, 32);
            float iq = 1.0f / fmaxf(sqrtf(ss), 1e-12f);
#pragma unroll
            for (int dt = 0; dt < 2; dt++)
#pragma unroll
                for (int r = 0; r < 4; r++) hq[dt][nt][r] = (f16)(aq_[dt][nt][r] * iq);
        }
    }
    {
        f32x4 ak_[2][4] = {};
#pragma unroll
        for (int ks = 0; ks < 6; ks++) {
            f16x8 af[4];
#pragma unroll
            for (int nt = 0; nt < 4; nt++)
                af[nt] = *(const f16x8*)(tok + (16 * nt + c16) * STOK + ks * 32 + 8 * g4);
#pragma unroll
            for (int dt = 0; dt < 2; dt++) {
                f16x8 wf = *(const f16x8*)(Wpk + (((size_t)(12 + 2 * w + dt) * 6 + ks) * 64 + l) * 8);
#pragma unroll
                for (int nt = 0; nt < 4; nt++)
                    ak_[dt][nt] = MFMA32(wf, af[nt], ak_[dt][nt]);
            }
        }
#pragma unroll
        for (int dt = 0; dt < 2; dt++) {
            f32x4 bb = *(const f32x4*)(bqkv + 192 + 32 * w + 16 * dt + 4 * g4);
#pragma unroll
            for (int nt = 0; nt < 4; nt++)
#pragma unroll
                for (int r = 0; r < 4; r++) ak_[dt][nt][r] += bb[r];
        }
#pragma unroll
        for (int nt = 0; nt < 4; nt++) {
            float ss = 0.f;
#pragma unroll
            for (int dt = 0; dt < 2; dt++)
#pragma unroll
                for (int r = 0; r < 4; r++) ss += ak_[dt][nt][r] * ak_[dt][nt][r];
            ss += __shfl_xor(ss, 16);
            ss += __shfl_xor(ss, 32);
            float ik = 1.0f / fmaxf(sqrtf(ss), 1e-12f);
#pragma unroll
            for (int dt = 0; dt < 2; dt++)
#pragma unroll
                for (int r = 0; r < 4; r++) hk[dt][nt][r] = (f16)(ak_[dt][nt][r] * ik);
        }
    }
    // ---- pass V (natural D[m][d]; output regs are exactly PV B-frags) ----
    f16x4 vb[2][4];   // [dt][mk]
    {
        f32x4 av_[2][4] = {};
#pragma unroll
        for (int ks = 0; ks < 6; ks++) {
            f16x8 af[4];
#pragma unroll
            for (int mt = 0; mt < 4; mt++)
                af[mt] = *(const f16x8*)(tok + (16 * mt + c16) * STOK + ks * 32 + 8 * g4);
#pragma unroll
            for (int dt = 0; dt < 2; dt++) {
                f16x8 wf = *(const f16x8*)(Wpk + (((size_t)(24 + 2 * w + dt) * 6 + ks) * 64 + l) * 8);
#pragma unroll
                for (int mt = 0; mt < 4; mt++)
                    av_[dt][mt] = MFMA32(af[mt], wf, av_[dt][mt]);
            }
        }
#pragma unroll
        for (int dt = 0; dt < 2; dt++) {
            float bb = bqkv[384 + 32 * w + 16 * dt + c16];
#pragma unroll
            for (int mt = 0; mt < 4; mt++)
#pragma unroll
                for (int r = 0; r < 4; r++) vb[dt][mt][r] = (f16)(av_[dt][mt][r] + bb);
        }
    }

    __syncthreads();   // all waves done reading tok -> qk may overlay

    // ---- write Qhat/Khat (swizzled, own-wave region; read back same-wave) ----
    f16* qh = qk + (w * 2 + 0) * 2048;
    f16* kh = qk + (w * 2 + 1) * 2048;
#pragma unroll
    for (int nt = 0; nt < 4; nt++)
#pragma unroll
        for (int dt = 0; dt < 2; dt++) {
            int base = qkidx(16 * nt + c16, 16 * dt + 4 * g4);
            *(f16x2*)(qh + base)     = f16x2{hq[dt][nt][0], hq[dt][nt][1]};
            *(f16x2*)(qh + base + 2) = f16x2{hq[dt][nt][2], hq[dt][nt][3]};
            *(f16x2*)(kh + base)     = f16x2{hk[dt][nt][0], hk[dt][nt][1]};
            *(f16x2*)(kh + base + 2) = f16x2{hk[dt][nt][2], hk[dt][nt][3]};
        }

    // ---- phase 2: attention (own head, own window) ----
    const float itau_l2 = LOG2E / fmaxf(tau[w], 0.01f);
    const float* cb = comb + ((size_t)((b & 63) * NH + w)) * (NT * NT);
    f32x4 av[4][2];
    attn_one(qh, kh, cb, itau_l2, vb, c16, g4, av);

    __syncthreads();   // all qk reads done -> ao may overlay

    // ao[n][c' = 32w+16dt+c16]
#pragma unroll
    for (int nt = 0; nt < 4; nt++)
#pragma unroll
        for (int dt = 0; dt < 2; dt++)
#pragma unroll
            for (int r = 0; r < 4; r++)
                ao[(16 * nt + 4 * g4 + r) * STOK + 32 * w + 16 * dt + c16] = (f16)av[nt][dt][r];
    __syncthreads();

    // ---- phase 3: proj GEMM, wave (win,w) -> output c-tiles {2w, 2w+1} of own window ----
    f32x4 acc2[2][4] = {};
#pragma unroll
    for (int ks = 0; ks < 6; ks++) {
        f16x8 af[4];
#pragma unroll
        for (int rt = 0; rt < 4; rt++)
            af[rt] = *(const f16x8*)(ao + (16 * rt + c16) * STOK + ks * 32 + 8 * g4);
#pragma unroll
        for (int c2 = 0; c2 < 2; c2++) {
            f16x8 bw = *(const f16x8*)(Wpp + (((size_t)(2 * w + c2) * 6 + ks) * 64 + l) * 8);
#pragma unroll
            for (int rt = 0; rt < 4; rt++)
                acc2[c2][rt] = MFMA32(af[rt], bw, acc2[c2][rt]);
        }
    }
    float* ob = out + (size_t)b * (CH * NT);
#pragma unroll
    for (int c2 = 0; c2 < 2; c2++) {
        int c = 16 * (2 * w + c2) + c16;
        float bp = bproj[c];
#pragma unroll
        for (int rt = 0; rt < 4; rt++) {
            f32x4 o4 = acc2[c2][rt];
            o4[0] += bp; o4[1] += bp; o4[2] += bp; o4[3] += bp;
            *(f32x4*)(ob + c * NT + 16 * rt + 4 * g4) = o4;
        }
    }
}

// ---------------- launcher ----------------
#define WS_BIAS 0
#define WS_WPK  98304
#define WS_WPP  319488
#define WS_COMB 393216

extern "C" void kernel_launch(void* const* d_in, const int* in_sizes, int n_in,
                              void* d_out, int out_size, void* d_ws, size_t ws_size,
                              hipStream_t stream) {
    const float* x     = (const float*)d_in[0];
    const float* mask  = (const float*)d_in[1];
    const float* Wqkv  = (const float*)d_in[2];
    const float* bqkv  = (const float*)d_in[3];
    const float* Wproj = (const float*)d_in[4];
    const float* bproj = (const float*)d_in[5];
    const float* mW1   = (const float*)d_in[6];
    const float* mb1   = (const float*)d_in[7];
    const float* mW2   = (const float*)d_in[8];
    const float* mb2   = (const float*)d_in[9];
    const float* tau   = (const float*)d_in[10];

    char* ws = (char*)d_ws;
    float* bias_tbl = (float*)(ws + WS_BIAS);
    f16*   Wpk      = (f16*)(ws + WS_WPK);
    f16*   Wpp      = (f16*)(ws + WS_WPP);
    float* comb     = (float*)(ws + WS_COMB);

    bias_kernel<<<16, 256, 0, stream>>>(mW1, mb1, mW2, mb2, bias_tbl);
    int prep_n = 36 * 6 * 64 * 8 + 12 * 6 * 64 * 8;
    prep_kernel<<<(prep_n + 255) / 256, 256, 0, stream>>>(Wqkv, Wproj, Wpk, Wpp);
    int comb_n = 64 * NH * NT * NT;
    comb_kernel<<<(comb_n + 255) / 256, 256, 0, stream>>>(mask, bias_tbl, comb);
    attn_kernel<<<BWIN / 2, 768, 0, stream>>>(x, bqkv, bproj, tau, Wpk, Wpp, comb,
                                              (float*)d_out);
}

// Round 11
// 330.341 us; speedup vs baseline: 1.2549x; 1.0578x over previous
//
#include <hip/hip_runtime.h>

typedef _Float16 f16;
typedef _Float16 f16x2 __attribute__((ext_vector_type(2)));
typedef _Float16 f16x4 __attribute__((ext_vector_type(4)));
typedef _Float16 f16x8 __attribute__((ext_vector_type(8)));
typedef float f32x4 __attribute__((ext_vector_type(4)));

#define NT 64
#define CH 192
#define NH 6
#define MH 256
#define BWIN 4096
#define LOG2E 1.44269504f

#define STOK 200            // tok/ao row stride (f16): 400 B
#define SMEM_FUSED 49152    // fused fallback LDS
#define SMEM_SPLIT 25600    // tok/ao only

#define MFMA16(a, b, c) __builtin_amdgcn_mfma_f32_16x16x16f16(a, b, c, 0, 0, 0)
#define MFMA32(a, b, c) __builtin_amdgcn_mfma_f32_16x16x32_f16(a, b, c, 0, 0, 0)

// swizzled index into a [64][32] f16 qk tile (fused fallback only)
__device__ __forceinline__ int qkidx(int n, int d) {
    return n * 32 + ((((d >> 3) + (n >> 1)) & 3) << 3) + (d & 7);
}

// ---------------- bias table ----------------
__global__ void bias_kernel(const float* __restrict__ mW1, const float* __restrict__ mb1,
                            const float* __restrict__ mW2, const float* __restrict__ mb2,
                            float* __restrict__ bias_tbl) {
    int p = blockIdx.x * blockDim.x + threadIdx.x;
    if (p >= NT * NT) return;
    int n = p >> 6, m = p & 63;
    float di = (float)((n >> 3) - (m >> 3));
    float dj = (float)((n & 7) - (m & 7));
    float r0 = copysignf(log1pf(fabsf(di)), di);
    float r1 = copysignf(log1pf(fabsf(dj)), dj);
    float acc[NH];
#pragma unroll
    for (int h = 0; h < NH; h++) acc[h] = mb2[h];
    for (int k = 0; k < MH; k++) {
        float hv = fmaxf(r0 * mW1[k] + r1 * mW1[MH + k] + mb1[k], 0.0f);
#pragma unroll
        for (int h = 0; h < NH; h++) acc[h] += hv * mW2[k * NH + h];
    }
#pragma unroll
    for (int h = 0; h < NH; h++) bias_tbl[h * (NT * NT) + p] = acc[h];
}

// ---------------- fragment-packed weight prep ----------------
__global__ void prep_kernel(const float* __restrict__ Wqkv, const float* __restrict__ Wproj,
                            f16* __restrict__ Wpk, f16* __restrict__ Wpp) {
    int i = blockIdx.x * blockDim.x + threadIdx.x;
    const int NQ = 36 * 6 * 64 * 8;
    if (i < NQ) {
        int t = i & 7, lane = (i >> 3) & 63, ks = (i >> 9) % 6, ct = i >> 9; ct /= 6;
        int o = 16 * ct + (lane & 15);
        int c = ks * 32 + (lane >> 4) * 8 + t;
        Wpk[i] = (f16)Wqkv[c * 576 + o];
    } else if (i < NQ + 12 * 6 * 64 * 8) {
        int j = i - NQ;
        int t = j & 7, lane = (j >> 3) & 63, ks = (j >> 9) % 6, ct = j >> 9; ct /= 6;
        int o = 16 * ct + (lane & 15);
        int c = ks * 32 + (lane >> 4) * 8 + t;
        Wpp[j] = (f16)Wproj[c * 192 + o];
    }
}

// ---------------- combined (mask + bias) * log2e table ----------------
__global__ void comb_kernel(const float* __restrict__ mask, const float* __restrict__ bias_tbl,
                            float* __restrict__ comb) {
    int j = blockIdx.x * blockDim.x + threadIdx.x;
    if (j >= 64 * NH * NT * NT) return;
    int im = j / (NH * NT * NT);
    int rem = j % (NH * NT * NT);
    int h = rem >> 12;
    int p = rem & 4095;
    comb[j] = (mask[im * 4096 + p] + bias_tbl[h * 4096 + p]) * LOG2E;
}

// =======================================================================
// SPLIT PATH K1: qkv GEMM + norm -> ws     (r6 phases 0-1; stores to ws)
// ws per (window,head) 12KB: qhat [64][32], khat [64][32], v frag-packed
// =======================================================================
__launch_bounds__(384)
__global__ void qkv_kernel(const float* __restrict__ x, const float* __restrict__ bqkv,
                           const f16* __restrict__ Wpk, f16* __restrict__ qkv_ws) {
    __shared__ __align__(16) f16 tok[NT * STOK];

    const int tid = threadIdx.x;
    const int l   = tid & 63;
    const int w   = __builtin_amdgcn_readfirstlane(tid >> 6);
    const int b   = blockIdx.x;
    const int c16 = l & 15;
    const int g4  = l >> 4;

    // stage x[b] (fp32 [c][n]) -> tok f16 [n][c]
    {
        const float* xb = x + (size_t)b * (CH * NT);
        const int n4 = 4 * c16;
#pragma unroll
        for (int i = 0; i < 4; i++) {
            int c = 32 * w + 8 * g4 + 2 * i;
            f32x4 a0 = *(const f32x4*)(xb + c * NT + n4);
            f32x4 a1 = *(const f32x4*)(xb + (c + 1) * NT + n4);
#pragma unroll
            for (int j = 0; j < 4; j++) {
                f16x2 p;
                p[0] = (f16)a0[j];
                p[1] = (f16)a1[j];
                *(f16x2*)(tok + (n4 + j) * STOK + c) = p;
            }
        }
    }
    __syncthreads();

    f16* dstq = qkv_ws + (size_t)(b * NH + w) * 6144;
    f16* dstk = dstq + 2048;
    f16* dstv = dstq + 4096;

    // pass Q (transposed D[d][n])
    {
        f32x4 acc[2][4] = {};
#pragma unroll
        for (int ks = 0; ks < 6; ks++) {
            f16x8 af[4];
#pragma unroll
            for (int nt = 0; nt < 4; nt++)
                af[nt] = *(const f16x8*)(tok + (16 * nt + c16) * STOK + ks * 32 + 8 * g4);
#pragma unroll
            for (int dt = 0; dt < 2; dt++) {
                f16x8 wf = *(const f16x8*)(Wpk + (((size_t)(2 * w + dt) * 6 + ks) * 64 + l) * 8);
#pragma unroll
                for (int nt = 0; nt < 4; nt++)
                    acc[dt][nt] = MFMA32(wf, af[nt], acc[dt][nt]);
            }
        }
        f32x4 bb0 = *(const f32x4*)(bqkv + 32 * w + 4 * g4);
        f32x4 bb1 = *(const f32x4*)(bqkv + 32 * w + 16 + 4 * g4);
#pragma unroll
        for (int nt = 0; nt < 4; nt++) {
            float a0[4], a1[4];
            float ss = 0.f;
#pragma unroll
            for (int r = 0; r < 4; r++) {
                a0[r] = acc[0][nt][r] + bb0[r];
                a1[r] = acc[1][nt][r] + bb1[r];
                ss += a0[r] * a0[r] + a1[r] * a1[r];
            }
            ss += __shfl_xor(ss, 16);
            ss += __shfl_xor(ss, 32);
            float inv = 1.0f / fmaxf(sqrtf(ss), 1e-12f);
            f16x4 h0, h1;
#pragma unroll
            for (int r = 0; r < 4; r++) {
                h0[r] = (f16)(a0[r] * inv);
                h1[r] = (f16)(a1[r] * inv);
            }
            *(f16x4*)(dstq + (16 * nt + c16) * 32 + 4 * g4)      = h0;
            *(f16x4*)(dstq + (16 * nt + c16) * 32 + 16 + 4 * g4) = h1;
        }
    }
    // pass K
    {
        f32x4 acc[2][4] = {};
#pragma unroll
        for (int ks = 0; ks < 6; ks++) {
            f16x8 af[4];
#pragma unroll
            for (int nt = 0; nt < 4; nt++)
                af[nt] = *(const f16x8*)(tok + (16 * nt + c16) * STOK + ks * 32 + 8 * g4);
#pragma unroll
            for (int dt = 0; dt < 2; dt++) {
                f16x8 wf = *(const f16x8*)(Wpk + (((size_t)(12 + 2 * w + dt) * 6 + ks) * 64 + l) * 8);
#pragma unroll
                for (int nt = 0; nt < 4; nt++)
                    acc[dt][nt] = MFMA32(wf, af[nt], acc[dt][nt]);
            }
        }
        f32x4 bb0 = *(const f32x4*)(bqkv + CH + 32 * w + 4 * g4);
        f32x4 bb1 = *(const f32x4*)(bqkv + CH + 32 * w + 16 + 4 * g4);
#pragma unroll
        for (int nt = 0; nt < 4; nt++) {
            float a0[4], a1[4];
            float ss = 0.f;
#pragma unroll
            for (int r = 0; r < 4; r++) {
                a0[r] = acc[0][nt][r] + bb0[r];
                a1[r] = acc[1][nt][r] + bb1[r];
                ss += a0[r] * a0[r] + a1[r] * a1[r];
            }
            ss += __shfl_xor(ss, 16);
            ss += __shfl_xor(ss, 32);
            float inv = 1.0f / fmaxf(sqrtf(ss), 1e-12f);
            f16x4 h0, h1;
#pragma unroll
            for (int r = 0; r < 4; r++) {
                h0[r] = (f16)(a0[r] * inv);
                h1[r] = (f16)(a1[r] * inv);
            }
            *(f16x4*)(dstk + (16 * nt + c16) * 32 + 4 * g4)      = h0;
            *(f16x4*)(dstk + (16 * nt + c16) * 32 + 16 + 4 * g4) = h1;
        }
    }
    // pass V (natural D[m][d]) -> fragment-packed store
    {
        f32x4 acc[2][4] = {};
#pragma unroll
        for (int ks = 0; ks < 6; ks++) {
            f16x8 af[4];
#pragma unroll
            for (int mt = 0; mt < 4; mt++)
                af[mt] = *(const f16x8*)(tok + (16 * mt + c16) * STOK + ks * 32 + 8 * g4);
#pragma unroll
            for (int dt = 0; dt < 2; dt++) {
                f16x8 wf = *(const f16x8*)(Wpk + (((size_t)(24 + 2 * w + dt) * 6 + ks) * 64 + l) * 8);
#pragma unroll
                for (int mt = 0; mt < 4; mt++)
                    acc[dt][mt] = MFMA32(af[mt], wf, acc[dt][mt]);
            }
        }
#pragma unroll
        for (int dt = 0; dt < 2; dt++) {
            float bb = bqkv[384 + 32 * w + 16 * dt + c16];
#pragma unroll
            for (int mt = 0; mt < 4; mt++) {
                f16x4 h;
#pragma unroll
                for (int r = 0; r < 4; r++) h[r] = (f16)(acc[dt][mt][r] + bb);
                *(f16x4*)(dstv + ((dt * 4 + mt) * 64 + l) * 4) = h;
            }
        }
    }
}

// =======================================================================
// SPLIT PATH K23: attention + proj        (r6 phases 2-3; reads ws)
// =======================================================================
__launch_bounds__(384)
__global__ void attn2_kernel(const float* __restrict__ tau, const f16* __restrict__ Wpp,
                             const float* __restrict__ bproj, const float* __restrict__ comb,
                             const f16* __restrict__ qkv_ws, float* __restrict__ out) {
    __shared__ __align__(16) f16 ao[NT * STOK];

    const int tid = threadIdx.x;
    const int l   = tid & 63;
    const int w   = __builtin_amdgcn_readfirstlane(tid >> 6);
    const int b   = blockIdx.x;
    const int c16 = l & 15;
    const int g4  = l >> 4;

    const f16* qg = qkv_ws + (size_t)(b * NH + w) * 6144;
    const f16* kg = qg + 2048;
    const f16* vg = qg + 4096;

    // V PV-B-frags (coalesced f16x4 lane loads)
    f16x4 vb[2][4];
#pragma unroll
    for (int dt = 0; dt < 2; dt++)
#pragma unroll
        for (int mk = 0; mk < 4; mk++)
            vb[dt][mk] = *(const f16x4*)(vg + ((dt * 4 + mk) * 64 + l) * 4);

    const float itau_l2 = LOG2E / fmaxf(tau[w], 0.01f);
    const float* cb = comb + ((size_t)((b & 63) * NH + w)) * (NT * NT);

    // attention in two nt-halves (keeps S-tile at 32 regs)
#pragma unroll
    for (int half = 0; half < 2; half++) {
        f16x8 aqf[2];
#pragma unroll
        for (int ntl = 0; ntl < 2; ntl++)
            aqf[ntl] = *(const f16x8*)(qg + (16 * (2 * half + ntl) + c16) * 32 + 8 * g4);
        f32x4 sv[4][2];   // [mt][ntl]
#pragma unroll
        for (int mt = 0; mt < 4; mt++) {
            f16x8 akf = *(const f16x8*)(kg + (16 * mt + c16) * 32 + 8 * g4);
#pragma unroll
            for (int ntl = 0; ntl < 2; ntl++) {
                f32x4 z = {};
                sv[mt][ntl] = MFMA32(akf, aqf[ntl], z);
            }
        }
        // epilogue: scale + comb
#pragma unroll
        for (int mt = 0; mt < 4; mt++)
#pragma unroll
            for (int ntl = 0; ntl < 2; ntl++) {
                int nt = 2 * half + ntl;
                f32x4 cc = *(const f32x4*)(cb + (16 * nt + c16) * NT + 16 * mt + 4 * g4);
#pragma unroll
                for (int r = 0; r < 4; r++)
                    sv[mt][ntl][r] = sv[mt][ntl][r] * itau_l2 + cc[r];
            }
        // softmax over m, fold 1/sum
#pragma unroll
        for (int ntl = 0; ntl < 2; ntl++) {
            float mx = sv[0][ntl][0];
#pragma unroll
            for (int mt = 0; mt < 4; mt++)
#pragma unroll
                for (int r = 0; r < 4; r++) mx = fmaxf(mx, sv[mt][ntl][r]);
            mx = fmaxf(mx, __shfl_xor(mx, 16));
            mx = fmaxf(mx, __shfl_xor(mx, 32));
            float sum = 0.f;
#pragma unroll
            for (int mt = 0; mt < 4; mt++)
#pragma unroll
                for (int r = 0; r < 4; r++) {
                    float p = exp2f(sv[mt][ntl][r] - mx);
                    sv[mt][ntl][r] = p;
                    sum += p;
                }
            sum += __shfl_xor(sum, 16);
            sum += __shfl_xor(sum, 32);
            float ris = 1.0f / sum;
#pragma unroll
            for (int mt = 0; mt < 4; mt++)
#pragma unroll
                for (int r = 0; r < 4; r++) sv[mt][ntl][r] *= ris;
        }
        // P frags + PV
        f16x4 pa[4][2];
#pragma unroll
        for (int mk = 0; mk < 4; mk++)
#pragma unroll
            for (int ntl = 0; ntl < 2; ntl++) {
                f16x4 h;
#pragma unroll
                for (int r = 0; r < 4; r++) h[r] = (f16)sv[mk][ntl][r];
                pa[mk][ntl] = h;
            }
        f32x4 av[2][2] = {};
#pragma unroll
        for (int mk = 0; mk < 4; mk++)
#pragma unroll
            for (int ntl = 0; ntl < 2; ntl++)
#pragma unroll
                for (int dt = 0; dt < 2; dt++)
                    av[ntl][dt] = MFMA16(pa[mk][ntl], vb[dt][mk], av[ntl][dt]);
        // write ao LDS rows (n = 16*(2half+ntl)+4g4+r, c' = 32w+16dt+c16)
#pragma unroll
        for (int ntl = 0; ntl < 2; ntl++)
#pragma unroll
            for (int dt = 0; dt < 2; dt++)
#pragma unroll
                for (int r = 0; r < 4; r++)
                    ao[(16 * (2 * half + ntl) + 4 * g4 + r) * STOK + 32 * w + 16 * dt + c16] =
                        (f16)av[ntl][dt][r];
    }
    __syncthreads();

    // proj GEMM (r6 phase 3 verbatim)
    f32x4 acc2[2][4] = {};
#pragma unroll
    for (int ks = 0; ks < 6; ks++) {
        f16x8 af[4];
#pragma unroll
        for (int rt = 0; rt < 4; rt++)
            af[rt] = *(const f16x8*)(ao + (16 * rt + c16) * STOK + ks * 32 + 8 * g4);
#pragma unroll
        for (int c2 = 0; c2 < 2; c2++) {
            f16x8 bw = *(const f16x8*)(Wpp + (((size_t)(2 * w + c2) * 6 + ks) * 64 + l) * 8);
#pragma unroll
            for (int rt = 0; rt < 4; rt++)
                acc2[c2][rt] = MFMA32(af[rt], bw, acc2[c2][rt]);
        }
    }
    float* ob = out + (size_t)b * (CH * NT);
#pragma unroll
    for (int c2 = 0; c2 < 2; c2++) {
        int c = 16 * (2 * w + c2) + c16;
        float bp = bproj[c];
#pragma unroll
        for (int rt = 0; rt < 4; rt++) {
            f32x4 o4 = acc2[c2][rt];
            o4[0] += bp; o4[1] += bp; o4[2] += bp; o4[3] += bp;
            *(f32x4*)(ob + c * NT + 16 * rt + 4 * g4) = o4;
        }
    }
}

// =======================================================================
// FUSED FALLBACK (r6 kernel, proven 338 us) — used when ws is too small
// =======================================================================
__launch_bounds__(384)
__global__ void attn_fused_kernel(const float* __restrict__ x, const float* __restrict__ bqkv,
                                  const float* __restrict__ bproj, const float* __restrict__ tau,
                                  const f16* __restrict__ Wpk, const f16* __restrict__ Wpp,
                                  const float* __restrict__ comb, float* __restrict__ out) {
    __shared__ __align__(16) char smem[SMEM_FUSED];
    f16* tok = (f16*)smem;
    f16* qk  = (f16*)smem;
    f16* ao  = (f16*)smem;

    const int b   = blockIdx.x;
    const int tid = threadIdx.x;
    const int l   = tid & 63;
    const int w   = __builtin_amdgcn_readfirstlane(tid >> 6);
    const int c16 = l & 15;
    const int g4  = l >> 4;

    {
        const float* xb = x + (size_t)b * (CH * NT);
        const int n4 = 4 * c16;
#pragma unroll
        for (int i = 0; i < 4; i++) {
            int c = 32 * w + 8 * g4 + 2 * i;
            f32x4 a0 = *(const f32x4*)(xb + c * NT + n4);
            f32x4 a1 = *(const f32x4*)(xb + (c + 1) * NT + n4);
#pragma unroll
            for (int j = 0; j < 4; j++) {
                f16x2 p;
                p[0] = (f16)a0[j];
                p[1] = (f16)a1[j];
                *(f16x2*)(tok + (n4 + j) * STOK + c) = p;
            }
        }
    }
    __syncthreads();

    f16x4 hq[2][4], hk[2][4];
    {
        f32x4 aq_[2][4] = {};
#pragma unroll
        for (int ks = 0; ks < 6; ks++) {
            f16x8 af[4];
#pragma unroll
            for (int nt = 0; nt < 4; nt++)
                af[nt] = *(const f16x8*)(tok + (16 * nt + c16) * STOK + ks * 32 + 8 * g4);
#pragma unroll
            for (int dt = 0; dt < 2; dt++) {
                f16x8 wf = *(const f16x8*)(Wpk + (((size_t)(2 * w + dt) * 6 + ks) * 64 + l) * 8);
#pragma unroll
                for (int nt = 0; nt < 4; nt++)
                    aq_[dt][nt] = MFMA32(wf, af[nt], aq_[dt][nt]);
            }
        }
#pragma unroll
        for (int dt = 0; dt < 2; dt++) {
            f32x4 bb = *(const f32x4*)(bqkv + 32 * w + 16 * dt + 4 * g4);
#pragma unroll
            for (int nt = 0; nt < 4; nt++)
#pragma unroll
                for (int r = 0; r < 4; r++) aq_[dt][nt][r] += bb[r];
        }
#pragma unroll
        for (int nt = 0; nt < 4; nt++) {
            float ss = 0.f;
#pragma unroll
            for (int dt = 0; dt < 2; dt++)
#pragma unroll
                for (int r = 0; r < 4; r++) ss += aq_[dt][nt][r] * aq_[dt][nt][r];
            ss += __shfl_xor(ss, 16);
            ss += __shfl_xor(ss, 32);
            float iq = 1.0f / fmaxf(sqrtf(ss), 1e-12f);
#pragma unroll
            for (int dt = 0; dt < 2; dt++)
#pragma unroll
                for (int r = 0; r < 4; r++) hq[dt][nt][r] = (f16)(aq_[dt][nt][r] * iq);
        }
    }
    {
        f32x4 ak_[2][4] = {};
#pragma unroll
        for (int ks = 0; ks < 6; ks++) {
            f16x8 af[4];
#pragma unroll
            for (int nt = 0; nt < 4; nt++)
                af[nt] = *(const f16x8*)(tok + (16 * nt + c16) * STOK + ks * 32 + 8 * g4);
#pragma unroll
            for (int dt = 0; dt < 2; dt++) {
                f16x8 wf = *(const f16x8*)(Wpk + (((size_t)(12 + 2 * w + dt) * 6 + ks) * 64 + l) * 8);
#pragma unroll
                for (int nt = 0; nt < 4; nt++)
                    ak_[dt][nt] = MFMA32(wf, af[nt], ak_[dt][nt]);
            }
        }
#pragma unroll
        for (int dt = 0; dt < 2; dt++) {
            f32x4 bb = *(const f32x4*)(bqkv + 192 + 32 * w + 16 * dt + 4 * g4);
#pragma unroll
            for (int nt = 0; nt < 4; nt++)
#pragma unroll
                for (int r = 0; r < 4; r++) ak_[dt][nt][r] += bb[r];
        }
#pragma unroll
        for (int nt = 0; nt < 4; nt++) {
            float ss = 0.f;
#pragma unroll
            for (int dt = 0; dt < 2; dt++)
#pragma unroll
                for (int r = 0; r < 4; r++) ss += ak_[dt][nt][r] * ak_[dt][nt][r];
            ss += __shfl_xor(ss, 16);
            ss += __shfl_xor(ss, 32);
            float ik = 1.0f / fmaxf(sqrtf(ss), 1e-12f);
#pragma unroll
            for (int dt = 0; dt < 2; dt++)
#pragma unroll
                for (int r = 0; r < 4; r++) hk[dt][nt][r] = (f16)(ak_[dt][nt][r] * ik);
        }
    }
    f16x4 vb[2][4];
    {
        f32x4 av_[2][4] = {};
#pragma unroll
        for (int ks = 0; ks < 6; ks++) {
            f16x8 af[4];
#pragma unroll
            for (int mt = 0; mt < 4; mt++)
                af[mt] = *(const f16x8*)(tok + (16 * mt + c16) * STOK + ks * 32 + 8 * g4);
#pragma unroll
            for (int dt = 0; dt < 2; dt++) {
                f16x8 wf = *(const f16x8*)(Wpk + (((size_t)(24 + 2 * w + dt) * 6 + ks) * 64 + l) * 8);
#pragma unroll
                for (int mt = 0; mt < 4; mt++)
                    av_[dt][mt] = MFMA32(af[mt], wf, av_[dt][mt]);
            }
        }
#pragma unroll
        for (int dt = 0; dt < 2; dt++) {
            float bb = bqkv[384 + 32 * w + 16 * dt + c16];
#pragma unroll
            for (int mt = 0; mt < 4; mt++)
#pragma unroll
                for (int r = 0; r < 4; r++) vb[dt][mt][r] = (f16)(av_[dt][mt][r] + bb);
        }
    }
    __syncthreads();

    f16* qh = qk + (w * 2 + 0) * 2048;
    f16* kh = qk + (w * 2 + 1) * 2048;
#pragma unroll
    for (int nt = 0; nt < 4; nt++)
#pragma unroll
        for (int dt = 0; dt < 2; dt++) {
            int base = qkidx(16 * nt + c16, 16 * dt + 4 * g4);
            *(f16x2*)(qh + base)     = f16x2{hq[dt][nt][0], hq[dt][nt][1]};
            *(f16x2*)(qh + base + 2) = f16x2{hq[dt][nt][2], hq[dt][nt][3]};
            *(f16x2*)(kh + base)     = f16x2{hk[dt][nt][0], hk[dt][nt][1]};
            *(f16x2*)(kh + base + 2) = f16x2{hk[dt][nt][2], hk[dt][nt][3]};
        }

    f32x4 sv[4][4];
    {
        f16x8 aqf[4];
#pragma unroll
        for (int t = 0; t < 4; t++)
            aqf[t] = *(const f16x8*)(qh + qkidx(16 * t + c16, 8 * g4));
#pragma unroll
        for (int mt = 0; mt < 4; mt++) {
            f16x8 akf = *(const f16x8*)(kh + qkidx(16 * mt + c16, 8 * g4));
#pragma unroll
            for (int nt = 0; nt < 4; nt++) {
                f32x4 z = {};
                sv[mt][nt] = MFMA32(akf, aqf[nt], z);
            }
        }
    }
    {
        const float itau_l2 = LOG2E / fmaxf(tau[w], 0.01f);
        const float* cb = comb + ((size_t)((b & 63) * NH + w)) * (NT * NT);
#pragma unroll
        for (int mt = 0; mt < 4; mt++)
#pragma unroll
            for (int nt = 0; nt < 4; nt++) {
                f32x4 cc = *(const f32x4*)(cb + (16 * nt + c16) * NT + 16 * mt + 4 * g4);
#pragma unroll
                for (int r = 0; r < 4; r++)
                    sv[mt][nt][r] = sv[mt][nt][r] * itau_l2 + cc[r];
            }
    }
#pragma unroll
    for (int nt = 0; nt < 4; nt++) {
        float mx = sv[0][nt][0];
#pragma unroll
        for (int mt = 0; mt < 4; mt++)
#pragma unroll
            for (int r = 0; r < 4; r++) mx = fmaxf(mx, sv[mt][nt][r]);
        mx = fmaxf(mx, __shfl_xor(mx, 16));
        mx = fmaxf(mx, __shfl_xor(mx, 32));
        float sum = 0.f;
#pragma unroll
        for (int mt = 0; mt < 4; mt++)
#pragma unroll
            for (int r = 0; r < 4; r++) {
                float p = exp2f(sv[mt][nt][r] - mx);
                sv[mt][nt][r] = p;
                sum += p;
            }
        sum += __shfl_xor(sum, 16);
        sum += __shfl_xor(sum, 32);
        float ris = 1.0f / sum;
#pragma unroll
        for (int mt = 0; mt < 4; mt++)
#pragma unroll
            for (int r = 0; r < 4; r++) sv[mt][nt][r] *= ris;
    }
    f16x4 pa[4][4];
#pragma unroll
    for (int mk = 0; mk < 4; mk++)
#pragma unroll
        for (int nt = 0; nt < 4; nt++) {
            f16x4 h;
#pragma unroll
            for (int r = 0; r < 4; r++) h[r] = (f16)sv[mk][nt][r];
            pa[mk][nt] = h;
        }
    f32x4 av[4][2] = {};
#pragma unroll
    for (int mk = 0; mk < 4; mk++)
#pragma unroll
        for (int nt = 0; nt < 4; nt++)
#pragma unroll
            for (int dt = 0; dt < 2; dt++)
                av[nt][dt] = MFMA16(pa[mk][nt], vb[dt][mk], av[nt][dt]);

    __syncthreads();
#pragma unroll
    for (int nt = 0; nt < 4; nt++)
#pragma unroll
        for (int dt = 0; dt < 2; dt++)
#pragma unroll
            for (int r = 0; r < 4; r++)
                ao[(16 * nt + 4 * g4 + r) * STOK + 32 * w + 16 * dt + c16] = (f16)av[nt][dt][r];
    __syncthreads();

    f32x4 acc2[2][4] = {};
#pragma unroll
    for (int ks = 0; ks < 6; ks++) {
        f16x8 af[4];
#pragma unroll
        for (int rt = 0; rt < 4; rt++)
            af[rt] = *(const f16x8*)(ao + (16 * rt + c16) * STOK + ks * 32 + 8 * g4);
#pragma unroll
        for (int c2 = 0; c2 < 2; c2++) {
            f16x8 bw = *(const f16x8*)(Wpp + (((size_t)(2 * w + c2) * 6 + ks) * 64 + l) * 8);
#pragma unroll
            for (int rt = 0; rt < 4; rt++)
                acc2[c2][rt] = MFMA32(af[rt], bw, acc2[c2][rt]);
        }
    }
    float* ob = out + (size_t)b * (CH * NT);
#pragma unroll
    for (int c2 = 0; c2 < 2; c2++) {
        int c = 16 * (2 * w + c2) + c16;
        float bp = bproj[c];
#pragma unroll
        for (int rt = 0; rt < 4; rt++) {
            f32x4 o4 = acc2[c2][rt];
            o4[0] += bp; o4[1] += bp; o4[2] += bp; o4[3] += bp;
            *(f32x4*)(ob + c * NT + 16 * rt + 4 * g4) = o4;
        }
    }
}

// ---------------- launcher ----------------
#define WS_BIAS 0
#define WS_WPK  98304
#define WS_WPP  319488
#define WS_COMB 393216
#define WS_QKV  6684672
#define WS_NEED ((size_t)WS_QKV + (size_t)BWIN * NH * 6144 * 2)  // qkv ws in bytes

extern "C" void kernel_launch(void* const* d_in, const int* in_sizes, int n_in,
                              void* d_out, int out_size, void* d_ws, size_t ws_size,
                              hipStream_t stream) {
    const float* x     = (const float*)d_in[0];
    const float* mask  = (const float*)d_in[1];
    const float* Wqkv  = (const float*)d_in[2];
    const float* bqkv  = (const float*)d_in[3];
    const float* Wproj = (const float*)d_in[4];
    const float* bproj = (const float*)d_in[5];
    const float* mW1   = (const float*)d_in[6];
    const float* mb1   = (const float*)d_in[7];
    const float* mW2   = (const float*)d_in[8];
    const float* mb2   = (const float*)d_in[9];
    const float* tau   = (const float*)d_in[10];

    char* ws = (char*)d_ws;
    float* bias_tbl = (float*)(ws + WS_BIAS);
    f16*   Wpk      = (f16*)(ws + WS_WPK);
    f16*   Wpp      = (f16*)(ws + WS_WPP);
    float* comb     = (float*)(ws + WS_COMB);
    f16*   qkv_ws   = (f16*)(ws + WS_QKV);

    bias_kernel<<<16, 256, 0, stream>>>(mW1, mb1, mW2, mb2, bias_tbl);
    int prep_n = 36 * 6 * 64 * 8 + 12 * 6 * 64 * 8;
    prep_kernel<<<(prep_n + 255) / 256, 256, 0, stream>>>(Wqkv, Wproj, Wpk, Wpp);
    int comb_n = 64 * NH * NT * NT;
    comb_kernel<<<(comb_n + 255) / 256, 256, 0, stream>>>(mask, bias_tbl, comb);

    if (ws_size >= WS_NEED) {
        qkv_kernel<<<BWIN, 384, 0, stream>>>(x, bqkv, Wpk, qkv_ws);
        attn2_kernel<<<BWIN, 384, 0, stream>>>(tau, Wpp, bproj, comb, qkv_ws, (float*)d_out);
    } else {
        attn_fused_kernel<<<BWIN, 384, 0, stream>>>(x, bqkv, bproj, tau, Wpk, Wpp, comb,
                                                    (float*)d_out);
    }
}